// Round 1
// baseline (412.328 us; speedup 1.0000x reference)
//
#include <hip/hip_runtime.h>
#include <hip/hip_bf16.h>
#include <math.h>

typedef __attribute__((ext_vector_type(4))) float f32x4;
typedef __attribute__((ext_vector_type(8))) __bf16 bf16x8;
typedef __attribute__((ext_vector_type(8))) unsigned short u16x8;

#define HID    2048
#define NHEADS 8
#define HDIM   256
#define SEQ    2048
#define BATCH  2
#define ROWS   (BATCH*SEQ)                 // 4096
#define QKVN   (NHEADS*HDIM + 2*HDIM)      // 2560

#define GM_F32    0
#define GM_BF16   1
#define GM_SCORES 2
#define GM_PV     3

typedef __attribute__((address_space(1))) const void gvoid_t;
typedef __attribute__((address_space(3))) void lvoid_t;

__device__ __forceinline__ void gload16(const void* g, void* l){
  __builtin_amdgcn_global_load_lds((gvoid_t*)g, (lvoid_t*)l, 16, 0, 0);
}

__device__ __forceinline__ float bf2f(unsigned short u){
  union { unsigned int i; float f; } x; x.i = ((unsigned int)u) << 16; return x.f;
}
__device__ __forceinline__ unsigned short f2bf(float f){
  union { float f; unsigned int i; } x; x.f = f;
  unsigned int u = x.i;
  return (unsigned short)((u + 0x7FFFu + ((u >> 16) & 1u)) >> 16);
}

// ---------------- f32 -> bf16 bulk convert (16 elems/thread) ----------------
__global__ __launch_bounds__(256)
void k_f32_to_bf16(const float* __restrict__ src, unsigned short* __restrict__ dst){
  long i = ((long)blockIdx.x * 256 + threadIdx.x) * 16;
  f32x4 x0 = *(const f32x4*)(src + i);
  f32x4 x1 = *(const f32x4*)(src + i + 4);
  f32x4 x2 = *(const f32x4*)(src + i + 8);
  f32x4 x3 = *(const f32x4*)(src + i + 12);
  u16x8 w0, w1;
  #pragma unroll
  for (int j = 0; j < 4; ++j){
    w0[j]   = f2bf(x0[j]);
    w0[4+j] = f2bf(x1[j]);
    w1[j]   = f2bf(x2[j]);
    w1[4+j] = f2bf(x3[j]);
  }
  *(u16x8*)(dst + i)     = w0;
  *(u16x8*)(dst + i + 8) = w1;
}

// ------------- transpose f32 (rows x cols) -> bf16 (cols x rows) ------------
__global__ __launch_bounds__(256)
void k_transpose(const float* __restrict__ src, unsigned short* __restrict__ dst,
                 int srcCols, int dstLd){
  __shared__ float t[32][33];
  int bx = blockIdx.x * 32;           // src col base
  int by = blockIdx.y * 32;           // src row base
  int tx = threadIdx.x & 31, ty = threadIdx.x >> 5;   // ty 0..7
  #pragma unroll
  for (int i = 0; i < 4; ++i){
    int rr = ty + i*8;
    t[rr][tx] = src[(long)(by + rr)*srcCols + bx + tx];
  }
  __syncthreads();
  #pragma unroll
  for (int i = 0; i < 4; ++i){
    int rr = ty + i*8;
    dst[(long)(bx + rr)*dstLd + by + tx] = f2bf(t[tx][rr]);
  }
}

// ---------------- RoPE + split qkv -> Qb, Kb, VT ----------------
__global__ __launch_bounds__(256)
void k_rope(const unsigned short* __restrict__ qkv, const int* __restrict__ pos_ids,
            unsigned short* __restrict__ Qb, unsigned short* __restrict__ Kb,
            unsigned short* __restrict__ VT){
  int row = blockIdx.x;               // 0..4095  (b*2048+s)
  int b = row >> 11, s = row & (SEQ - 1);
  float pos = (float)pos_ids[row];
  int tid = threadIdx.x;
  const unsigned short* r = qkv + (long)row * QKVN;

  #pragma unroll
  for (int it = 0; it < 4; ++it){
    int p = it*256 + tid;             // 0..1023 : q pairs
    int d = p & 127, h = p >> 7;
    int col = h*HDIM + d;
    float inv = (float)exp((double)d * -0.07195578415606393);
    float ang = pos * inv;
    float sn, cs; sincosf(ang, &sn, &cs);
    float x0 = bf2f(r[col]), x1 = bf2f(r[col + 128]);
    Qb[(long)row*HID + col]       = f2bf(x0*cs - x1*sn);
    Qb[(long)row*HID + col + 128] = f2bf(x1*cs + x0*sn);
  }
  if (tid < 128){
    int d = tid;
    float inv = (float)exp((double)d * -0.07195578415606393);
    float ang = pos * inv;
    float sn, cs; sincosf(ang, &sn, &cs);
    float x0 = bf2f(r[HID + d]), x1 = bf2f(r[HID + d + 128]);
    Kb[(long)row*HDIM + d]       = f2bf(x0*cs - x1*sn);
    Kb[(long)row*HDIM + d + 128] = f2bf(x1*cs + x0*sn);
  }
  {
    int d = tid;                      // v transpose-copy (bf16 bits unchanged)
    VT[((long)b*HDIM + d)*SEQ + s] = r[HID + HDIM + d];
  }
}

// ---------------- row softmax, in place, causal ----------------
__global__ __launch_bounds__(256)
void k_softmax(float* __restrict__ S){
  long row = blockIdx.x;              // (b*8+h)*2048 + sq
  int sq = (int)(row & (SEQ - 1));
  float* p = S + row * (long)SEQ;
  int tid = threadIdx.x, lane = tid & 63, w = tid >> 6;
  int base = tid * 8;
  f32x4 a = *(f32x4*)(p + base);
  f32x4 bvec = *(f32x4*)(p + base + 4);
  float v[8];
  #pragma unroll
  for (int j = 0; j < 8; ++j){
    float x = (j < 4) ? a[j] : bvec[j-4];
    v[j] = (base + j <= sq) ? x : -__builtin_inff();
  }
  float mx = v[0];
  #pragma unroll
  for (int j = 1; j < 8; ++j) mx = fmaxf(mx, v[j]);
  #pragma unroll
  for (int off = 32; off; off >>= 1) mx = fmaxf(mx, __shfl_xor(mx, off));
  __shared__ float red[8];
  if (lane == 0) red[w] = mx;
  __syncthreads();
  mx = fmaxf(fmaxf(red[0], red[1]), fmaxf(red[2], red[3]));
  float e[8];
  float sum = 0.f;
  #pragma unroll
  for (int j = 0; j < 8; ++j){
    e[j] = (base + j <= sq) ? __expf(v[j] - mx) : 0.f;
    sum += e[j];
  }
  #pragma unroll
  for (int off = 32; off; off >>= 1) sum += __shfl_xor(sum, off);
  if (lane == 0) red[4 + w] = sum;
  __syncthreads();
  sum = (red[4] + red[5]) + (red[6] + red[7]);
  float inv = 1.0f / sum;
  f32x4 o0, o1;
  #pragma unroll
  for (int j = 0; j < 4; ++j){ o0[j] = e[j]*inv; o1[j] = e[4+j]*inv; }
  *(f32x4*)(p + base)     = o0;
  *(f32x4*)(p + base + 4) = o1;
}

// ---------------- generic 128x128 MFMA GEMM, C = A @ BT^T ----------------
// A: (M x K) bf16 (or f32 for GM_PV), lda; BT: (N x K) bf16, ldb; C: ldc.
// blockIdx.z decomposed as (zb, zh) = (z / nH, z % nH) with per-operand strides.
template<int MODE>
__global__ __launch_bounds__(256)
void gemm_bt(const void* __restrict__ Av, const unsigned short* __restrict__ BT0,
             void* __restrict__ Cv,
             int M, int N, int K, int lda, int ldb, int ldc,
             long a_sb, long a_sh, long b_sb, long b_sh, long c_sb, long c_sh,
             int nH, float scale){
  constexpr int BM = 128, BN = 128, BK = 32;
  int m0 = blockIdx.x * BM, n0 = blockIdx.y * BN;
  if (MODE == GM_SCORES && n0 > m0 + BM - 1) return;   // fully-masked tile

  int z = blockIdx.z;
  int zb = z / nH, zh = z % nH;

  const unsigned short* A16 = nullptr;
  const float* A32 = nullptr;
  if constexpr (MODE == GM_PV) A32 = (const float*)Av + zb*a_sb + zh*a_sh;
  else                         A16 = (const unsigned short*)Av + zb*a_sb + zh*a_sh;
  const unsigned short* BT = BT0 + zb*b_sb + zh*b_sh;

  __shared__ unsigned short lA[BM*BK];
  __shared__ unsigned short lB[BN*BK];

  int tid = threadIdx.x, lane = tid & 63, w = tid >> 6;
  int wr = w >> 1, wc = w & 1;
  int lrow = lane & 15, lk = (lane >> 4) * 8;

  f32x4 acc[4][4];
  #pragma unroll
  for (int m = 0; m < 4; ++m)
    #pragma unroll
    for (int n = 0; n < 4; ++n)
      #pragma unroll
      for (int q = 0; q < 4; ++q) acc[m][n][q] = 0.f;

  int kend = (MODE == GM_PV) ? ((m0 + BM < K) ? (m0 + BM) : K) : K;

  for (int k0 = 0; k0 < kend; k0 += BK){
    // ---- stage A tile [BM][BK] ----
    if constexpr (MODE == GM_PV){
      int r = tid >> 1, cb = (tid & 1) * 16;
      const float* src = A32 + (long)(m0 + r)*lda + k0 + cb;
      f32x4 x0 = *(const f32x4*)(src);
      f32x4 x1 = *(const f32x4*)(src + 4);
      f32x4 x2 = *(const f32x4*)(src + 8);
      f32x4 x3 = *(const f32x4*)(src + 12);
      u16x8 w0, w1;
      #pragma unroll
      for (int j = 0; j < 4; ++j){
        w0[j]   = f2bf(x0[j]);
        w0[4+j] = f2bf(x1[j]);
        w1[j]   = f2bf(x2[j]);
        w1[4+j] = f2bf(x3[j]);
      }
      *(u16x8*)&lA[r*BK + cb]     = w0;
      *(u16x8*)&lA[r*BK + cb + 8] = w1;
    } else {
      #pragma unroll
      for (int t = 0; t < 2; ++t){
        int seg = w*2 + t;
        const unsigned short* src = A16 + (long)(m0 + seg*16 + (lane >> 2))*lda + k0 + (lane & 3)*8;
        gload16(src, &lA[seg*512]);
      }
    }
    // ---- stage B tile [BN][BK] ----
    #pragma unroll
    for (int t = 0; t < 2; ++t){
      int seg = w*2 + t;
      const unsigned short* src = BT + (long)(n0 + seg*16 + (lane >> 2))*ldb + k0 + (lane & 3)*8;
      gload16(src, &lB[seg*512]);
    }
    __syncthreads();

    bf16x8 af[4], bfr[4];
    #pragma unroll
    for (int m = 0; m < 4; ++m)
      af[m] = *(const bf16x8*)&lA[(wr*64 + m*16 + lrow)*BK + lk];
    #pragma unroll
    for (int n = 0; n < 4; ++n)
      bfr[n] = *(const bf16x8*)&lB[(wc*64 + n*16 + lrow)*BK + lk];
    #pragma unroll
    for (int m = 0; m < 4; ++m)
      #pragma unroll
      for (int n = 0; n < 4; ++n)
        acc[m][n] = __builtin_amdgcn_mfma_f32_16x16x32_bf16(af[m], bfr[n], acc[m][n], 0, 0, 0);
    __syncthreads();
  }

  // ---- epilogue ----
  long cbase = zb*c_sb + zh*c_sh;
  #pragma unroll
  for (int m = 0; m < 4; ++m){
    #pragma unroll
    for (int ri = 0; ri < 4; ++ri){
      int orow = m0 + wr*64 + m*16 + (lane >> 4)*4 + ri;
      #pragma unroll
      for (int n = 0; n < 4; ++n){
        int ocol = n0 + wc*64 + n*16 + (lane & 15);
        float vv = acc[m][n][ri];
        if (MODE == GM_SCORES){
          if (ocol <= orow) ((float*)Cv)[cbase + (long)orow*ldc + ocol] = vv * scale;
        } else if (MODE == GM_F32){
          ((float*)Cv)[cbase + (long)orow*ldc + ocol] = vv;
        } else {
          ((unsigned short*)Cv)[cbase + (long)orow*ldc + ocol] = f2bf(vv);
        }
      }
    }
  }
}

extern "C" void kernel_launch(void* const* d_in, const int* in_sizes, int n_in,
                              void* d_out, int out_size, void* d_ws, size_t ws_size,
                              hipStream_t stream){
  const float* hs  = (const float*)d_in[0];
  const int*   pos = (const int*)  d_in[1];
  // d_in[2] = attention_mask: causal, applied analytically — unused.
  const float* Wq  = (const float*)d_in[3];
  const float* Wk  = (const float*)d_in[4];
  const float* Wv  = (const float*)d_in[5];
  const float* Wo  = (const float*)d_in[6];

  float* out  = (float*)d_out;
  float* Sbuf = out + (long)ROWS * HID;       // attn_weights region (B,H,S,S) f32

  unsigned short* wsp   = (unsigned short*)d_ws;
  unsigned short* hsb   = wsp;                                   // 4096x2048
  unsigned short* wqkvT = hsb   + (long)ROWS*HID;                // 2560x2048
  unsigned short* woT   = wqkvT + (long)QKVN*HID;                // 2048x2048
  unsigned short* qkvb  = woT   + (long)HID*HID;                 // 4096x2560
  unsigned short* Qb    = qkvb  + (long)ROWS*QKVN;               // 4096x2048
  unsigned short* Kb    = Qb    + (long)ROWS*HID;                // 4096x256
  unsigned short* VT    = Kb    + (long)ROWS*HDIM;               // 2x256x2048
  unsigned short* AOb   = VT    + (long)BATCH*HDIM*SEQ;          // 4096x2048

  // 1. converts / weight transposes
  k_f32_to_bf16<<<(ROWS*HID)/(256*16), 256, 0, stream>>>(hs, hsb);
  k_transpose<<<dim3(HID/32,  HID/32), 256, 0, stream>>>(Wq, wqkvT, HID, HID);
  k_transpose<<<dim3(HDIM/32, HID/32), 256, 0, stream>>>(Wk, wqkvT + (long)HID*HID, HDIM, HID);
  k_transpose<<<dim3(HDIM/32, HID/32), 256, 0, stream>>>(Wv, wqkvT + (long)(HID+HDIM)*HID, HDIM, HID);
  k_transpose<<<dim3(HID/32,  HID/32), 256, 0, stream>>>(Wo, woT, HID, HID);

  // 2. QKV projection (bf16 out)
  gemm_bt<GM_BF16><<<dim3(ROWS/128, QKVN/128, 1), 256, 0, stream>>>(
      hsb, wqkvT, qkvb, ROWS, QKVN, HID, HID, HID, QKVN,
      0, 0, 0, 0, 0, 0, 1, 1.f);

  // 3. RoPE + split
  k_rope<<<ROWS, 256, 0, stream>>>(qkvb, pos, Qb, Kb, VT);

  // 4. scores = scale * Q K^T (causal), raw into attn_weights region
  gemm_bt<GM_SCORES><<<dim3(SEQ/128, SEQ/128, BATCH*NHEADS), 256, 0, stream>>>(
      Qb, Kb, Sbuf, SEQ, SEQ, HDIM, HID, HDIM, SEQ,
      (long)SEQ*HID, (long)HDIM,
      (long)SEQ*HDIM, 0,
      (long)NHEADS*SEQ*SEQ, (long)SEQ*SEQ,
      NHEADS, 0.0625f);

  // 5. softmax in place (writes exact zeros in masked region)
  k_softmax<<<BATCH*NHEADS*SEQ, 256, 0, stream>>>(Sbuf);

  // 6. attn_out = P @ V   (P read f32 from output buffer, reg-staged to bf16)
  gemm_bt<GM_PV><<<dim3(SEQ/128, HDIM/128, BATCH*NHEADS), 256, 0, stream>>>(
      Sbuf, VT, AOb, SEQ, HDIM, SEQ, SEQ, SEQ, HID,
      (long)NHEADS*SEQ*SEQ, (long)SEQ*SEQ,
      (long)HDIM*SEQ, 0,
      (long)SEQ*HID, (long)HDIM,
      NHEADS, 1.f);

  // 7. out = attn_out @ Wo (f32 out)
  gemm_bt<GM_F32><<<dim3(ROWS/128, HID/128, 1), 256, 0, stream>>>(
      AOb, woT, out, ROWS, HID, HID, HID, HID, HID,
      0, 0, 0, 0, 0, 0, 1, 1.f);
}

// Round 2
// 397.175 us; speedup vs baseline: 1.0382x; 1.0382x over previous
//
#include <hip/hip_runtime.h>
#include <hip/hip_bf16.h>
#include <math.h>

typedef __attribute__((ext_vector_type(4))) float f32x4;
typedef __attribute__((ext_vector_type(8))) __bf16 bf16x8;
typedef __attribute__((ext_vector_type(8))) unsigned short u16x8;
typedef __attribute__((ext_vector_type(4))) unsigned short u16x4;

#define HID    2048
#define NHEADS 8
#define HDIM   256
#define SEQ    2048
#define BATCH  2
#define ROWS   (BATCH*SEQ)                 // 4096
#define QKVN   (NHEADS*HDIM + 2*HDIM)      // 2560

#define GM_F32    0
#define GM_BF16   1
#define GM_SCORES 2

typedef __attribute__((address_space(1))) const void gvoid_t;
typedef __attribute__((address_space(3))) void lvoid_t;

__device__ __forceinline__ void gload16(const void* g, void* l){
  __builtin_amdgcn_global_load_lds((gvoid_t*)g, (lvoid_t*)l, 16, 0, 0);
}

__device__ __forceinline__ float bf2f(unsigned short u){
  union { unsigned int i; float f; } x; x.i = ((unsigned int)u) << 16; return x.f;
}
__device__ __forceinline__ unsigned short f2bf(float f){
  union { float f; unsigned int i; } x; x.f = f;
  unsigned int u = x.i;
  return (unsigned short)((u + 0x7FFFu + ((u >> 16) & 1u)) >> 16);
}

// ---------------- f32 -> bf16 bulk convert (16 elems/thread) ----------------
__global__ __launch_bounds__(256)
void k_f32_to_bf16(const float* __restrict__ src, unsigned short* __restrict__ dst){
  long i = ((long)blockIdx.x * 256 + threadIdx.x) * 16;
  f32x4 x0 = *(const f32x4*)(src + i);
  f32x4 x1 = *(const f32x4*)(src + i + 4);
  f32x4 x2 = *(const f32x4*)(src + i + 8);
  f32x4 x3 = *(const f32x4*)(src + i + 12);
  u16x8 w0, w1;
  #pragma unroll
  for (int j = 0; j < 4; ++j){
    w0[j]   = f2bf(x0[j]);
    w0[4+j] = f2bf(x1[j]);
    w1[j]   = f2bf(x2[j]);
    w1[4+j] = f2bf(x3[j]);
  }
  *(u16x8*)(dst + i)     = w0;
  *(u16x8*)(dst + i + 8) = w1;
}

// ------------- transpose f32 (rows x cols) -> bf16 (cols x rows) ------------
__global__ __launch_bounds__(256)
void k_transpose(const float* __restrict__ src, unsigned short* __restrict__ dst,
                 int srcCols, int dstLd){
  __shared__ float t[32][33];
  int bx = blockIdx.x * 32;           // src col base
  int by = blockIdx.y * 32;           // src row base
  int tx = threadIdx.x & 31, ty = threadIdx.x >> 5;   // ty 0..7
  #pragma unroll
  for (int i = 0; i < 4; ++i){
    int rr = ty + i*8;
    t[rr][tx] = src[(long)(by + rr)*srcCols + bx + tx];
  }
  __syncthreads();
  #pragma unroll
  for (int i = 0; i < 4; ++i){
    int rr = ty + i*8;
    dst[(long)(bx + rr)*dstLd + by + tx] = f2bf(t[tx][rr]);
  }
}

// ---------------- RoPE + split qkv -> Qb, Kb, VT ----------------
__global__ __launch_bounds__(256)
void k_rope(const unsigned short* __restrict__ qkv, const int* __restrict__ pos_ids,
            unsigned short* __restrict__ Qb, unsigned short* __restrict__ Kb,
            unsigned short* __restrict__ VT){
  int row = blockIdx.x;               // 0..4095  (b*2048+s)
  int b = row >> 11, s = row & (SEQ - 1);
  float pos = (float)pos_ids[row];
  int tid = threadIdx.x;
  const unsigned short* r = qkv + (long)row * QKVN;

  #pragma unroll
  for (int it = 0; it < 4; ++it){
    int p = it*256 + tid;             // 0..1023 : q pairs
    int d = p & 127, h = p >> 7;
    int col = h*HDIM + d;
    float inv = (float)exp((double)d * -0.07195578415606393);
    float ang = pos * inv;
    float sn, cs; sincosf(ang, &sn, &cs);
    float x0 = bf2f(r[col]), x1 = bf2f(r[col + 128]);
    Qb[(long)row*HID + col]       = f2bf(x0*cs - x1*sn);
    Qb[(long)row*HID + col + 128] = f2bf(x1*cs + x0*sn);
  }
  if (tid < 128){
    int d = tid;
    float inv = (float)exp((double)d * -0.07195578415606393);
    float ang = pos * inv;
    float sn, cs; sincosf(ang, &sn, &cs);
    float x0 = bf2f(r[HID + d]), x1 = bf2f(r[HID + d + 128]);
    Kb[(long)row*HDIM + d]       = f2bf(x0*cs - x1*sn);
    Kb[(long)row*HDIM + d + 128] = f2bf(x1*cs + x0*sn);
  }
  {
    int d = tid;                      // v transpose-copy (bf16 bits unchanged)
    VT[((long)b*HDIM + d)*SEQ + s] = r[HID + HDIM + d];
  }
}

// ------------- fused softmax + PV:  P = softmax(S) in place, AO = P @ V -------------
// Block: 256 threads / 4 waves. Handles two 32-row q-strips {p, 63-p} (balanced causal work).
// Wave w computes O[32 rows][w*64 .. w*64+63] (m=2, n=4 fragments).
__global__ __launch_bounds__(256)
void k_pvsm(float* __restrict__ S, const unsigned short* __restrict__ VT,
            unsigned short* __restrict__ AOb){
  constexpr int QB = 32, BK = 32;
  int bh = blockIdx.z; int b = bh >> 3, h = bh & 7;
  float* Sh = S + (long)bh * SEQ * SEQ;
  const unsigned short* Vb = VT + (long)b * HDIM * SEQ;

  __shared__ unsigned short lA[QB*BK];        // P tile bf16   (32x32)
  __shared__ unsigned short lB[HDIM*BK];      // V tile bf16   (256x32)
  __shared__ float mlm[QB], mli[QB];

  int tid = threadIdx.x, lane = tid & 63, w = tid >> 6;
  int prow = tid >> 3, pcb = (tid & 7) * 4;   // stage-P mapping: 8 thr/row, 16B each

  for (int s = 0; s < 2; ++s){
    int qtile = (s == 0) ? (int)blockIdx.x : (63 - (int)blockIdx.x);
    int qbase = qtile * QB;
    int kend  = qbase + QB;

    // ---- phase A: per-row online (max, sum) over valid cols ----
    for (int rr = 0; rr < 8; ++rr){
      int r = qbase + w*8 + rr;
      const float* row = Sh + (long)r * SEQ;
      float m = -__builtin_inff(), l = 0.f;
      for (int c0 = lane*4; c0 <= r; c0 += 256){
        f32x4 x = *(const f32x4*)(row + c0);
        float vm = -__builtin_inff();
        #pragma unroll
        for (int j = 0; j < 4; ++j) if (c0 + j <= r) vm = fmaxf(vm, x[j]);
        if (vm > m){ l = (l > 0.f) ? l * __expf(m - vm) : 0.f; m = vm; }
        #pragma unroll
        for (int j = 0; j < 4; ++j) if (c0 + j <= r) l += __expf(x[j] - m);
      }
      #pragma unroll
      for (int off = 32; off; off >>= 1){
        float om = __shfl_xor(m, off), ol = __shfl_xor(l, off);
        float nm = fmaxf(m, om);
        float t1 = (l  > 0.f) ? l  * __expf(m  - nm) : 0.f;
        float t2 = (ol > 0.f) ? ol * __expf(om - nm) : 0.f;
        m = nm; l = t1 + t2;
      }
      if (lane == 0){ mlm[w*8+rr] = m; mli[w*8+rr] = 1.0f / l; }
    }
    __syncthreads();

    float pm  = mlm[prow];
    float pil = mli[prow];
    int   rglob = qbase + prow;
    float* prowp = Sh + (long)rglob * SEQ;

    f32x4 acc[2][4];
    #pragma unroll
    for (int m = 0; m < 2; ++m)
      #pragma unroll
      for (int n = 0; n < 4; ++n)
        #pragma unroll
        for (int q = 0; q < 4; ++q) acc[m][n][q] = 0.f;

    // ---- phase B: K loop (stage P + V, MFMA) ----
    for (int k0 = 0; k0 < kend; k0 += BK){
      // stage P: read raw S, normalize, write back, bf16 to LDS
      f32x4 x = *(f32x4*)(prowp + k0 + pcb);
      u16x4 u;
      #pragma unroll
      for (int j = 0; j < 4; ++j){
        float p = (k0 + pcb + j <= rglob) ? __expf(x[j] - pm) * pil : 0.f;
        x[j] = p; u[j] = f2bf(p);
      }
      *(f32x4*)(prowp + k0 + pcb) = x;
      *(u16x4*)&lA[prow*BK + pcb] = u;
      // stage V tile (256 x 32) via global_load_lds
      #pragma unroll
      for (int t = 0; t < 4; ++t){
        int seg = w*4 + t;
        const unsigned short* src = Vb + (long)(seg*16 + (lane >> 2))*SEQ + k0 + (lane & 3)*8;
        gload16(src, &lB[seg*16*BK]);
      }
      __syncthreads();
      bf16x8 af[2], bfr[4];
      #pragma unroll
      for (int m = 0; m < 2; ++m)
        af[m] = *(const bf16x8*)&lA[(m*16 + (lane & 15))*BK + (lane >> 4)*8];
      #pragma unroll
      for (int n = 0; n < 4; ++n)
        bfr[n] = *(const bf16x8*)&lB[(w*64 + n*16 + (lane & 15))*BK + (lane >> 4)*8];
      #pragma unroll
      for (int m = 0; m < 2; ++m)
        #pragma unroll
        for (int n = 0; n < 4; ++n)
          acc[m][n] = __builtin_amdgcn_mfma_f32_16x16x32_bf16(af[m], bfr[n], acc[m][n], 0, 0, 0);
      __syncthreads();
    }

    // ---- zero tail (masked region of attn_weights) ----
    {
      f32x4 z4; z4[0]=0.f; z4[1]=0.f; z4[2]=0.f; z4[3]=0.f;
      for (int c0 = kend; c0 < SEQ; c0 += BK)
        *(f32x4*)(prowp + c0 + pcb) = z4;
    }

    // ---- epilogue: O -> AOb (bf16) ----
    #pragma unroll
    for (int m = 0; m < 2; ++m){
      #pragma unroll
      for (int ri = 0; ri < 4; ++ri){
        int row = qbase + m*16 + (lane >> 4)*4 + ri;
        long gr = (long)b*SEQ + row;
        #pragma unroll
        for (int n = 0; n < 4; ++n){
          int col = w*64 + n*16 + (lane & 15);
          AOb[gr*HID + h*HDIM + col] = f2bf(acc[m][n][ri]);
        }
      }
    }
    __syncthreads();
  }
}

// ---------------- generic 128x128 MFMA GEMM, C = A @ BT^T ----------------
template<int MODE>
__global__ __launch_bounds__(256)
void gemm_bt(const void* __restrict__ Av, const unsigned short* __restrict__ BT0,
             void* __restrict__ Cv,
             int M, int N, int K, int lda, int ldb, int ldc,
             long a_sb, long a_sh, long b_sb, long b_sh, long c_sb, long c_sh,
             int nH, float scale){
  constexpr int BM = 128, BN = 128, BK = 32;
  int m0 = blockIdx.x * BM, n0 = blockIdx.y * BN;
  if (MODE == GM_SCORES && n0 > m0 + BM - 1) return;   // fully-masked tile

  int z = blockIdx.z;
  int zb = z / nH, zh = z % nH;

  const unsigned short* A16 = (const unsigned short*)Av + zb*a_sb + zh*a_sh;
  const unsigned short* BT = BT0 + zb*b_sb + zh*b_sh;

  __shared__ unsigned short lA[BM*BK];
  __shared__ unsigned short lB[BN*BK];

  int tid = threadIdx.x, lane = tid & 63, w = tid >> 6;
  int wr = w >> 1, wc = w & 1;
  int lrow = lane & 15, lk = (lane >> 4) * 8;

  f32x4 acc[4][4];
  #pragma unroll
  for (int m = 0; m < 4; ++m)
    #pragma unroll
    for (int n = 0; n < 4; ++n)
      #pragma unroll
      for (int q = 0; q < 4; ++q) acc[m][n][q] = 0.f;

  for (int k0 = 0; k0 < K; k0 += BK){
    #pragma unroll
    for (int t = 0; t < 2; ++t){
      int seg = w*2 + t;
      const unsigned short* src = A16 + (long)(m0 + seg*16 + (lane >> 2))*lda + k0 + (lane & 3)*8;
      gload16(src, &lA[seg*512]);
    }
    #pragma unroll
    for (int t = 0; t < 2; ++t){
      int seg = w*2 + t;
      const unsigned short* src = BT + (long)(n0 + seg*16 + (lane >> 2))*ldb + k0 + (lane & 3)*8;
      gload16(src, &lB[seg*512]);
    }
    __syncthreads();

    bf16x8 af[4], bfr[4];
    #pragma unroll
    for (int m = 0; m < 4; ++m)
      af[m] = *(const bf16x8*)&lA[(wr*64 + m*16 + lrow)*BK + lk];
    #pragma unroll
    for (int n = 0; n < 4; ++n)
      bfr[n] = *(const bf16x8*)&lB[(wc*64 + n*16 + lrow)*BK + lk];
    #pragma unroll
    for (int m = 0; m < 4; ++m)
      #pragma unroll
      for (int n = 0; n < 4; ++n)
        acc[m][n] = __builtin_amdgcn_mfma_f32_16x16x32_bf16(af[m], bfr[n], acc[m][n], 0, 0, 0);
    __syncthreads();
  }

  // ---- epilogue ----
  long cbase = zb*c_sb + zh*c_sh;
  #pragma unroll
  for (int m = 0; m < 4; ++m){
    #pragma unroll
    for (int ri = 0; ri < 4; ++ri){
      int orow = m0 + wr*64 + m*16 + (lane >> 4)*4 + ri;
      #pragma unroll
      for (int n = 0; n < 4; ++n){
        int ocol = n0 + wc*64 + n*16 + (lane & 15);
        float vv = acc[m][n][ri];
        if (MODE == GM_SCORES){
          if (ocol <= orow) ((float*)Cv)[cbase + (long)orow*ldc + ocol] = vv * scale;
        } else if (MODE == GM_F32){
          ((float*)Cv)[cbase + (long)orow*ldc + ocol] = vv;
        } else {
          ((unsigned short*)Cv)[cbase + (long)orow*ldc + ocol] = f2bf(vv);
        }
      }
    }
  }
}

extern "C" void kernel_launch(void* const* d_in, const int* in_sizes, int n_in,
                              void* d_out, int out_size, void* d_ws, size_t ws_size,
                              hipStream_t stream){
  const float* hs  = (const float*)d_in[0];
  const int*   pos = (const int*)  d_in[1];
  // d_in[2] = attention_mask: causal, applied analytically — unused.
  const float* Wq  = (const float*)d_in[3];
  const float* Wk  = (const float*)d_in[4];
  const float* Wv  = (const float*)d_in[5];
  const float* Wo  = (const float*)d_in[6];

  float* out  = (float*)d_out;
  float* Sbuf = out + (long)ROWS * HID;       // attn_weights region (B,H,S,S) f32

  unsigned short* wsp   = (unsigned short*)d_ws;
  unsigned short* hsb   = wsp;                                   // 4096x2048
  unsigned short* wqkvT = hsb   + (long)ROWS*HID;                // 2560x2048
  unsigned short* woT   = wqkvT + (long)QKVN*HID;                // 2048x2048
  unsigned short* qkvb  = woT   + (long)HID*HID;                 // 4096x2560
  unsigned short* Qb    = qkvb  + (long)ROWS*QKVN;               // 4096x2048
  unsigned short* Kb    = Qb    + (long)ROWS*HID;                // 4096x256
  unsigned short* VT    = Kb    + (long)ROWS*HDIM;               // 2x256x2048
  unsigned short* AOb   = VT    + (long)BATCH*HDIM*SEQ;          // 4096x2048

  // 1. converts / weight transposes
  k_f32_to_bf16<<<(ROWS*HID)/(256*16), 256, 0, stream>>>(hs, hsb);
  k_transpose<<<dim3(HID/32,  HID/32), 256, 0, stream>>>(Wq, wqkvT, HID, HID);
  k_transpose<<<dim3(HDIM/32, HID/32), 256, 0, stream>>>(Wk, wqkvT + (long)HID*HID, HDIM, HID);
  k_transpose<<<dim3(HDIM/32, HID/32), 256, 0, stream>>>(Wv, wqkvT + (long)(HID+HDIM)*HID, HDIM, HID);
  k_transpose<<<dim3(HID/32,  HID/32), 256, 0, stream>>>(Wo, woT, HID, HID);

  // 2. QKV projection (bf16 out)
  gemm_bt<GM_BF16><<<dim3(ROWS/128, QKVN/128, 1), 256, 0, stream>>>(
      hsb, wqkvT, qkvb, ROWS, QKVN, HID, HID, HID, QKVN,
      0, 0, 0, 0, 0, 0, 1, 1.f);

  // 3. RoPE + split
  k_rope<<<ROWS, 256, 0, stream>>>(qkvb, pos, Qb, Kb, VT);

  // 4. scores = scale * Q K^T (causal), raw into attn_weights region
  gemm_bt<GM_SCORES><<<dim3(SEQ/128, SEQ/128, BATCH*NHEADS), 256, 0, stream>>>(
      Qb, Kb, Sbuf, SEQ, SEQ, HDIM, HID, HDIM, SEQ,
      (long)SEQ*HID, (long)HDIM,
      (long)SEQ*HDIM, 0,
      (long)NHEADS*SEQ*SEQ, (long)SEQ*SEQ,
      NHEADS, 0.0625f);

  // 5+6. fused softmax (in place, exact zeros in masked region) + PV
  k_pvsm<<<dim3(32, 1, BATCH*NHEADS), 256, 0, stream>>>(Sbuf, VT, AOb);

  // 7. out = attn_out @ Wo (f32 out)
  gemm_bt<GM_F32><<<dim3(ROWS/128, HID/128, 1), 256, 0, stream>>>(
      AOb, woT, out, ROWS, HID, HID, HID, HID, HID,
      0, 0, 0, 0, 0, 0, 1, 1.f);
}

// Round 3
// 389.963 us; speedup vs baseline: 1.0574x; 1.0185x over previous
//
#include <hip/hip_runtime.h>
#include <hip/hip_bf16.h>
#include <math.h>

typedef __attribute__((ext_vector_type(4))) float f32x4;
typedef __attribute__((ext_vector_type(8))) __bf16 bf16x8;
typedef __attribute__((ext_vector_type(8))) unsigned short u16x8;
typedef __attribute__((ext_vector_type(4))) unsigned short u16x4;

#define HID    2048
#define NHEADS 8
#define HDIM   256
#define SEQ    2048
#define BATCH  2
#define ROWS   (BATCH*SEQ)                 // 4096
#define QKVN   (NHEADS*HDIM + 2*HDIM)      // 2560
#define NBH    (BATCH*NHEADS)              // 16
#define NPTILE 32                          // 64-col partial tiles per row

#define GM_F32    0
#define GM_BF16   1
#define GM_SCORES 2

#define BIGNEG (-3.0e38f)

typedef __attribute__((address_space(1))) const void gvoid_t;
typedef __attribute__((address_space(3))) void lvoid_t;

__device__ __forceinline__ void gload16(const void* g, void* l){
  __builtin_amdgcn_global_load_lds((gvoid_t*)g, (lvoid_t*)l, 16, 0, 0);
}

__device__ __forceinline__ float bf2f(unsigned short u){
  union { unsigned int i; float f; } x; x.i = ((unsigned int)u) << 16; return x.f;
}
__device__ __forceinline__ unsigned short f2bf(float f){
  union { float f; unsigned int i; } x; x.f = f;
  unsigned int u = x.i;
  return (unsigned short)((u + 0x7FFFu + ((u >> 16) & 1u)) >> 16);
}

// ---------------- f32 -> bf16 bulk convert (16 elems/thread) ----------------
__global__ __launch_bounds__(256)
void k_f32_to_bf16(const float* __restrict__ src, unsigned short* __restrict__ dst){
  long i = ((long)blockIdx.x * 256 + threadIdx.x) * 16;
  f32x4 x0 = *(const f32x4*)(src + i);
  f32x4 x1 = *(const f32x4*)(src + i + 4);
  f32x4 x2 = *(const f32x4*)(src + i + 8);
  f32x4 x3 = *(const f32x4*)(src + i + 12);
  u16x8 w0, w1;
  #pragma unroll
  for (int j = 0; j < 4; ++j){
    w0[j]   = f2bf(x0[j]);
    w0[4+j] = f2bf(x1[j]);
    w1[j]   = f2bf(x2[j]);
    w1[4+j] = f2bf(x3[j]);
  }
  *(u16x8*)(dst + i)     = w0;
  *(u16x8*)(dst + i + 8) = w1;
}

// ------------- transpose f32 (rows x cols) -> bf16 (cols x rows) ------------
__global__ __launch_bounds__(256)
void k_transpose(const float* __restrict__ src, unsigned short* __restrict__ dst,
                 int srcCols, int dstLd){
  __shared__ float t[32][33];
  int bx = blockIdx.x * 32;           // src col base
  int by = blockIdx.y * 32;           // src row base
  int tx = threadIdx.x & 31, ty = threadIdx.x >> 5;   // ty 0..7
  #pragma unroll
  for (int i = 0; i < 4; ++i){
    int rr = ty + i*8;
    t[rr][tx] = src[(long)(by + rr)*srcCols + bx + tx];
  }
  __syncthreads();
  #pragma unroll
  for (int i = 0; i < 4; ++i){
    int rr = ty + i*8;
    dst[(long)(bx + rr)*dstLd + by + tx] = f2bf(t[tx][rr]);
  }
}

// ---------------- RoPE + split qkv -> Qb, Kb, VT ----------------
__global__ __launch_bounds__(256)
void k_rope(const unsigned short* __restrict__ qkv, const int* __restrict__ pos_ids,
            unsigned short* __restrict__ Qb, unsigned short* __restrict__ Kb,
            unsigned short* __restrict__ VT){
  int row = blockIdx.x;               // 0..4095  (b*2048+s)
  int b = row >> 11, s = row & (SEQ - 1);
  float pos = (float)pos_ids[row];
  int tid = threadIdx.x;
  const unsigned short* r = qkv + (long)row * QKVN;

  #pragma unroll
  for (int it = 0; it < 4; ++it){
    int p = it*256 + tid;             // 0..1023 : q pairs
    int d = p & 127, h = p >> 7;
    int col = h*HDIM + d;
    float inv = (float)exp((double)d * -0.07195578415606393);
    float ang = pos * inv;
    float sn, cs; sincosf(ang, &sn, &cs);
    float x0 = bf2f(r[col]), x1 = bf2f(r[col + 128]);
    Qb[(long)row*HID + col]       = f2bf(x0*cs - x1*sn);
    Qb[(long)row*HID + col + 128] = f2bf(x1*cs + x0*sn);
  }
  if (tid < 128){
    int d = tid;
    float inv = (float)exp((double)d * -0.07195578415606393);
    float ang = pos * inv;
    float sn, cs; sincosf(ang, &sn, &cs);
    float x0 = bf2f(r[HID + d]), x1 = bf2f(r[HID + d + 128]);
    Kb[(long)row*HDIM + d]       = f2bf(x0*cs - x1*sn);
    Kb[(long)row*HDIM + d + 128] = f2bf(x1*cs + x0*sn);
  }
  {
    int d = tid;                      // v transpose-copy (bf16 bits unchanged)
    VT[((long)b*HDIM + d)*SEQ + s] = r[HID + HDIM + d];
  }
}

// ------------- fused softmax + PV:  P = softmax(S) in place, AO = P @ V -------------
// Per-row (m,l) comes from partials emitted by the scores GEMM epilogue.
// Block: 256 threads / 4 waves; two 32-row q-strips {p, 63-p} (balanced causal work).
// Wave w computes O[32 rows][w*64 .. w*64+63]. BK=64, XOR-swizzled LDS.
__global__ __launch_bounds__(256)
void k_pvsm(float* __restrict__ S, const unsigned short* __restrict__ VT,
            unsigned short* __restrict__ AOb, const float* __restrict__ part){
  constexpr int QB = 32, BK = 64;
  int bh = blockIdx.z; int b = bh >> 3, h = bh & 7;
  float* Sh = S + (long)bh * SEQ * SEQ;
  const unsigned short* Vb = VT + (long)b * HDIM * SEQ;
  const float* pmb = part + (long)bh * NPTILE * SEQ;
  const float* plb = pmb + (long)NBH * NPTILE * SEQ;

  __shared__ unsigned short lA[QB*BK];        // P tile bf16 (32x64), swizzled
  __shared__ unsigned short lB[HDIM*BK];      // V tile bf16 (256x64), swizzled
  __shared__ float mlm[QB], mli[QB];

  int tid = threadIdx.x, lane = tid & 63, w = tid >> 6;
  int prow = tid >> 3, c8 = tid & 7;          // P-stage: 8 thr/row, 8 f32 each
  int vswz = ((lane & 7) ^ ((lane >> 3) & 7)) * 8;  // pre-swizzled V source col (elems)

  for (int s = 0; s < 2; ++s){
    int qtile = (s == 0) ? (int)blockIdx.x : (63 - (int)blockIdx.x);
    int qbase = qtile * QB;
    int kceil = (qbase + QB + 63) & ~63;

    // ---- phase A: combine per-tile partials -> (m, 1/l) per row ----
    {
      int r = qbase + prow;
      float m = BIGNEG, l = 0.f;
      int nt = (r >> 6) + 1;
      for (int tc = c8; tc < nt; tc += 8){
        float mt = pmb[(long)tc*SEQ + r], lt = plb[(long)tc*SEQ + r];
        float nm = fmaxf(m, mt);
        l = l*__expf(m - nm) + lt*__expf(mt - nm);
        m = nm;
      }
      #pragma unroll
      for (int off = 1; off < 8; off <<= 1){
        float om = __shfl_xor(m, off), ol = __shfl_xor(l, off);
        float nm = fmaxf(m, om);
        l = l*__expf(m - nm) + ol*__expf(om - nm);
        m = nm;
      }
      if (c8 == 0){ mlm[prow] = m; mli[prow] = 1.0f / l; }
    }
    __syncthreads();

    float pm  = mlm[prow];
    float pil = mli[prow];
    int   rglob = qbase + prow;
    float* prowp = Sh + (long)rglob * SEQ;

    f32x4 acc[2][4];
    #pragma unroll
    for (int m = 0; m < 2; ++m)
      #pragma unroll
      for (int n = 0; n < 4; ++n)
        #pragma unroll
        for (int q = 0; q < 4; ++q) acc[m][n][q] = 0.f;

    // ---- phase B: K loop ----
    for (int k0 = 0; k0 < kceil; k0 += BK){
      // stage P: read raw S, normalize, write back (incl. exact zeros), bf16 to LDS
      f32x4 x0 = *(f32x4*)(prowp + k0 + c8*8);
      f32x4 x1 = *(f32x4*)(prowp + k0 + c8*8 + 4);
      u16x8 u;
      #pragma unroll
      for (int j = 0; j < 4; ++j){
        float p0 = (k0 + c8*8 + j     <= rglob) ? __expf(x0[j] - pm) * pil : 0.f;
        float p1 = (k0 + c8*8 + 4 + j <= rglob) ? __expf(x1[j] - pm) * pil : 0.f;
        x0[j] = p0; x1[j] = p1;
        u[j] = f2bf(p0); u[4+j] = f2bf(p1);
      }
      *(f32x4*)(prowp + k0 + c8*8)     = x0;
      *(f32x4*)(prowp + k0 + c8*8 + 4) = x1;
      {
        int kb = (c8*16) ^ ((prow & 7) << 4);
        *(u16x8*)((char*)lA + prow*128 + kb) = u;
      }
      // stage V tile (256 x 64) via global_load_lds, pre-swizzled source
      #pragma unroll
      for (int t = 0; t < 8; ++t){
        int seg = w*8 + t;                         // 8 rows per 1KB segment
        const unsigned short* src = Vb + (long)(seg*8 + (lane >> 3))*SEQ + k0 + vswz;
        gload16(src, (char*)lB + seg*1024);
      }
      __syncthreads();

      #pragma unroll
      for (int kk = 0; kk < 2; ++kk){
        bf16x8 af[2];
        #pragma unroll
        for (int m = 0; m < 2; ++m){
          int row = m*16 + (lane & 15);
          int kb = (kk*64 + (lane >> 4)*16) ^ ((row & 7) << 4);
          af[m] = *(const bf16x8*)((char*)lA + row*128 + kb);
        }
        #pragma unroll
        for (int n = 0; n < 4; ++n){
          int vr = w*64 + n*16 + (lane & 15);
          int kb = (kk*64 + (lane >> 4)*16) ^ ((vr & 7) << 4);
          bf16x8 bfr = *(const bf16x8*)((char*)lB + vr*128 + kb);
          acc[0][n] = __builtin_amdgcn_mfma_f32_16x16x32_bf16(af[0], bfr, acc[0][n], 0, 0, 0);
          acc[1][n] = __builtin_amdgcn_mfma_f32_16x16x32_bf16(af[1], bfr, acc[1][n], 0, 0, 0);
        }
      }
      __syncthreads();
    }

    // ---- zero tail (masked region of attn_weights) ----
    {
      f32x4 z4; z4[0]=0.f; z4[1]=0.f; z4[2]=0.f; z4[3]=0.f;
      for (int c0 = kceil; c0 < SEQ; c0 += BK){
        *(f32x4*)(prowp + c0 + c8*8)     = z4;
        *(f32x4*)(prowp + c0 + c8*8 + 4) = z4;
      }
    }

    // ---- epilogue: O -> AOb (bf16) ----
    #pragma unroll
    for (int m = 0; m < 2; ++m){
      #pragma unroll
      for (int ri = 0; ri < 4; ++ri){
        int row = qbase + m*16 + (lane >> 4)*4 + ri;
        long gr = (long)b*SEQ + row;
        #pragma unroll
        for (int n = 0; n < 4; ++n){
          int col = w*64 + n*16 + (lane & 15);
          AOb[gr*HID + h*HDIM + col] = f2bf(acc[m][n][ri]);
        }
      }
    }
    __syncthreads();
  }
}

// ---------------- generic 128x128 MFMA GEMM, C = A @ BT^T ----------------
// GM_SCORES additionally emits per-(row, 64-col-tile) (max, sumexp) partials.
template<int MODE>
__global__ __launch_bounds__(256)
void gemm_bt(const void* __restrict__ Av, const unsigned short* __restrict__ BT0,
             void* __restrict__ Cv,
             int M, int N, int K, int lda, int ldb, int ldc,
             long a_sb, long a_sh, long b_sb, long b_sh, long c_sb, long c_sh,
             int nH, float scale, float* __restrict__ part){
  constexpr int BM = 128, BN = 128, BK = 32;
  int m0 = blockIdx.x * BM, n0 = blockIdx.y * BN;
  if (MODE == GM_SCORES && n0 > m0 + BM - 1) return;   // fully-masked tile

  int z = blockIdx.z;
  int zb = z / nH, zh = z % nH;

  const unsigned short* A16 = (const unsigned short*)Av + zb*a_sb + zh*a_sh;
  const unsigned short* BT = BT0 + zb*b_sb + zh*b_sh;

  __shared__ unsigned short lA[BM*BK];
  __shared__ unsigned short lB[BN*BK];

  int tid = threadIdx.x, lane = tid & 63, w = tid >> 6;
  int wr = w >> 1, wc = w & 1;
  int lrow = lane & 15, lk = (lane >> 4) * 8;

  f32x4 acc[4][4];
  #pragma unroll
  for (int m = 0; m < 4; ++m)
    #pragma unroll
    for (int n = 0; n < 4; ++n)
      #pragma unroll
      for (int q = 0; q < 4; ++q) acc[m][n][q] = 0.f;

  for (int k0 = 0; k0 < K; k0 += BK){
    #pragma unroll
    for (int t = 0; t < 2; ++t){
      int seg = w*2 + t;
      const unsigned short* src = A16 + (long)(m0 + seg*16 + (lane >> 2))*lda + k0 + (lane & 3)*8;
      gload16(src, &lA[seg*512]);
    }
    #pragma unroll
    for (int t = 0; t < 2; ++t){
      int seg = w*2 + t;
      const unsigned short* src = BT + (long)(n0 + seg*16 + (lane >> 2))*ldb + k0 + (lane & 3)*8;
      gload16(src, &lB[seg*512]);
    }
    __syncthreads();

    bf16x8 af[4], bfr[4];
    #pragma unroll
    for (int m = 0; m < 4; ++m)
      af[m] = *(const bf16x8*)&lA[(wr*64 + m*16 + lrow)*BK + lk];
    #pragma unroll
    for (int n = 0; n < 4; ++n)
      bfr[n] = *(const bf16x8*)&lB[(wc*64 + n*16 + lrow)*BK + lk];
    #pragma unroll
    for (int m = 0; m < 4; ++m)
      #pragma unroll
      for (int n = 0; n < 4; ++n)
        acc[m][n] = __builtin_amdgcn_mfma_f32_16x16x32_bf16(af[m], bfr[n], acc[m][n], 0, 0, 0);
    __syncthreads();
  }

  // ---- epilogue ----
  long cbase = zb*c_sb + zh*c_sh;
  if constexpr (MODE == GM_SCORES){
    int tc = (n0 + wc*64) >> 6;
    float* pm_out = part + ((long)z * NPTILE + tc) * SEQ;
    float* pl_out = pm_out + (long)NBH * NPTILE * SEQ;
    #pragma unroll
    for (int m = 0; m < 4; ++m){
      #pragma unroll
      for (int ri = 0; ri < 4; ++ri){
        int orow = m0 + wr*64 + m*16 + (lane >> 4)*4 + ri;
        float v[4]; bool ok[4];
        float mx = BIGNEG;
        #pragma unroll
        for (int n = 0; n < 4; ++n){
          int ocol = n0 + wc*64 + n*16 + (lane & 15);
          v[n] = acc[m][n][ri] * scale;
          ok[n] = (ocol <= orow);
          if (ok[n]){
            ((float*)Cv)[cbase + (long)orow*ldc + ocol] = v[n];
            mx = fmaxf(mx, v[n]);
          }
        }
        #pragma unroll
        for (int off = 8; off; off >>= 1) mx = fmaxf(mx, __shfl_xor(mx, off));
        float sm = 0.f;
        #pragma unroll
        for (int n = 0; n < 4; ++n) if (ok[n]) sm += __expf(v[n] - mx);
        #pragma unroll
        for (int off = 8; off; off >>= 1) sm += __shfl_xor(sm, off);
        if ((lane & 15) == 0){ pm_out[orow] = mx; pl_out[orow] = sm; }
      }
    }
  } else {
    #pragma unroll
    for (int m = 0; m < 4; ++m){
      #pragma unroll
      for (int ri = 0; ri < 4; ++ri){
        int orow = m0 + wr*64 + m*16 + (lane >> 4)*4 + ri;
        #pragma unroll
        for (int n = 0; n < 4; ++n){
          int ocol = n0 + wc*64 + n*16 + (lane & 15);
          float vv = acc[m][n][ri];
          if (MODE == GM_F32){
            ((float*)Cv)[cbase + (long)orow*ldc + ocol] = vv;
          } else {
            ((unsigned short*)Cv)[cbase + (long)orow*ldc + ocol] = f2bf(vv);
          }
        }
      }
    }
  }
}

extern "C" void kernel_launch(void* const* d_in, const int* in_sizes, int n_in,
                              void* d_out, int out_size, void* d_ws, size_t ws_size,
                              hipStream_t stream){
  const float* hs  = (const float*)d_in[0];
  const int*   pos = (const int*)  d_in[1];
  // d_in[2] = attention_mask: causal, applied analytically — unused.
  const float* Wq  = (const float*)d_in[3];
  const float* Wk  = (const float*)d_in[4];
  const float* Wv  = (const float*)d_in[5];
  const float* Wo  = (const float*)d_in[6];

  float* out  = (float*)d_out;
  float* Sbuf = out + (long)ROWS * HID;       // attn_weights region (B,H,S,S) f32

  unsigned short* wsp   = (unsigned short*)d_ws;
  unsigned short* hsb   = wsp;                                   // 4096x2048 (16.8MB)
  unsigned short* wqkvT = hsb   + (long)ROWS*HID;                // 2560x2048
  unsigned short* woT   = wqkvT + (long)QKVN*HID;                // 2048x2048
  unsigned short* qkvb  = woT   + (long)HID*HID;                 // 4096x2560
  unsigned short* Qb    = qkvb  + (long)ROWS*QKVN;               // 4096x2048
  unsigned short* Kb    = Qb    + (long)ROWS*HID;                // 4096x256
  unsigned short* VT    = Kb    + (long)ROWS*HDIM;               // 2x256x2048
  unsigned short* AOb   = VT    + (long)BATCH*HDIM*SEQ;          // 4096x2048

  // softmax partials (2 x 4MB) alias hsb — hsb is dead after the QKV GEMM.
  float* part = (float*)hsb;

  // 1. converts / weight transposes
  k_f32_to_bf16<<<(ROWS*HID)/(256*16), 256, 0, stream>>>(hs, hsb);
  k_transpose<<<dim3(HID/32,  HID/32), 256, 0, stream>>>(Wq, wqkvT, HID, HID);
  k_transpose<<<dim3(HDIM/32, HID/32), 256, 0, stream>>>(Wk, wqkvT + (long)HID*HID, HDIM, HID);
  k_transpose<<<dim3(HDIM/32, HID/32), 256, 0, stream>>>(Wv, wqkvT + (long)(HID+HDIM)*HID, HDIM, HID);
  k_transpose<<<dim3(HID/32,  HID/32), 256, 0, stream>>>(Wo, woT, HID, HID);

  // 2. QKV projection (bf16 out)
  gemm_bt<GM_BF16><<<dim3(ROWS/128, QKVN/128, 1), 256, 0, stream>>>(
      hsb, wqkvT, qkvb, ROWS, QKVN, HID, HID, HID, QKVN,
      0, 0, 0, 0, 0, 0, 1, 1.f, nullptr);

  // 3. RoPE + split
  k_rope<<<ROWS, 256, 0, stream>>>(qkvb, pos, Qb, Kb, VT);

  // 4. scores = scale * Q K^T (causal) into attn_weights region + (m,l) partials
  gemm_bt<GM_SCORES><<<dim3(SEQ/128, SEQ/128, NBH), 256, 0, stream>>>(
      Qb, Kb, Sbuf, SEQ, SEQ, HDIM, HID, HDIM, SEQ,
      (long)SEQ*HID, (long)HDIM,
      (long)SEQ*HDIM, 0,
      (long)NHEADS*SEQ*SEQ, (long)SEQ*SEQ,
      NHEADS, 0.0625f, part);

  // 5+6. fused softmax (in place, exact zeros in masked region) + PV
  k_pvsm<<<dim3(32, 1, NBH), 256, 0, stream>>>(Sbuf, VT, AOb, part);

  // 7. out = attn_out @ Wo (f32 out)
  gemm_bt<GM_F32><<<dim3(ROWS/128, HID/128, 1), 256, 0, stream>>>(
      AOb, woT, out, ROWS, HID, HID, HID, HID, HID,
      0, 0, 0, 0, 0, 0, 1, 1.f, nullptr);
}

// Round 4
// 371.543 us; speedup vs baseline: 1.1098x; 1.0496x over previous
//
#include <hip/hip_runtime.h>
#include <hip/hip_bf16.h>
#include <math.h>

typedef __attribute__((ext_vector_type(4))) float f32x4;
typedef __attribute__((ext_vector_type(8))) __bf16 bf16x8;
typedef __attribute__((ext_vector_type(8))) unsigned short u16x8;

#define HID    2048
#define NHEADS 8
#define HDIM   256
#define SEQ    2048
#define BATCH  2
#define ROWS   (BATCH*SEQ)                 // 4096
#define QKVN   (NHEADS*HDIM + 2*HDIM)      // 2560
#define NBH    (BATCH*NHEADS)              // 16
#define NPTILE 32                          // 64-col partial tiles per row

#define GM_F32    0
#define GM_BF16   1
#define GM_SCORES 2

#define BIGNEG (-3.0e38f)

typedef __attribute__((address_space(1))) const void gvoid_t;
typedef __attribute__((address_space(3))) void lvoid_t;

__device__ __forceinline__ void gload16(const void* g, void* l){
  __builtin_amdgcn_global_load_lds((gvoid_t*)g, (lvoid_t*)l, 16, 0, 0);
}

__device__ __forceinline__ float bf2f(unsigned short u){
  union { unsigned int i; float f; } x; x.i = ((unsigned int)u) << 16; return x.f;
}
__device__ __forceinline__ unsigned short f2bf(float f){
  union { float f; unsigned int i; } x; x.f = f;
  unsigned int u = x.i;
  return (unsigned short)((u + 0x7FFFu + ((u >> 16) & 1u)) >> 16);
}

// ---------------- f32 -> bf16 bulk convert (16 elems/thread) ----------------
__global__ __launch_bounds__(256)
void k_f32_to_bf16(const float* __restrict__ src, unsigned short* __restrict__ dst){
  long i = ((long)blockIdx.x * 256 + threadIdx.x) * 16;
  f32x4 x0 = *(const f32x4*)(src + i);
  f32x4 x1 = *(const f32x4*)(src + i + 4);
  f32x4 x2 = *(const f32x4*)(src + i + 8);
  f32x4 x3 = *(const f32x4*)(src + i + 12);
  u16x8 w0, w1;
  #pragma unroll
  for (int j = 0; j < 4; ++j){
    w0[j]   = f2bf(x0[j]);
    w0[4+j] = f2bf(x1[j]);
    w1[j]   = f2bf(x2[j]);
    w1[4+j] = f2bf(x3[j]);
  }
  *(u16x8*)(dst + i)     = w0;
  *(u16x8*)(dst + i + 8) = w1;
}

// ------------- transpose f32 (rows x cols) -> bf16 (cols x rows) ------------
__global__ __launch_bounds__(256)
void k_transpose(const float* __restrict__ src, unsigned short* __restrict__ dst,
                 int srcCols, int dstLd){
  __shared__ float t[32][33];
  int bx = blockIdx.x * 32;           // src col base
  int by = blockIdx.y * 32;           // src row base
  int tx = threadIdx.x & 31, ty = threadIdx.x >> 5;   // ty 0..7
  #pragma unroll
  for (int i = 0; i < 4; ++i){
    int rr = ty + i*8;
    t[rr][tx] = src[(long)(by + rr)*srcCols + bx + tx];
  }
  __syncthreads();
  #pragma unroll
  for (int i = 0; i < 4; ++i){
    int rr = ty + i*8;
    dst[(long)(bx + rr)*dstLd + by + tx] = f2bf(t[tx][rr]);
  }
}

// ---------------- RoPE + split qkv -> Qb, Kb, VT ----------------
__global__ __launch_bounds__(256)
void k_rope(const unsigned short* __restrict__ qkv, const int* __restrict__ pos_ids,
            unsigned short* __restrict__ Qb, unsigned short* __restrict__ Kb,
            unsigned short* __restrict__ VT){
  int row = blockIdx.x;               // 0..4095  (b*2048+s)
  int b = row >> 11, s = row & (SEQ - 1);
  float pos = (float)pos_ids[row];
  int tid = threadIdx.x;
  const unsigned short* r = qkv + (long)row * QKVN;

  #pragma unroll
  for (int it = 0; it < 4; ++it){
    int p = it*256 + tid;             // 0..1023 : q pairs
    int d = p & 127, h = p >> 7;
    int col = h*HDIM + d;
    float inv = (float)exp((double)d * -0.07195578415606393);
    float ang = pos * inv;
    float sn, cs; sincosf(ang, &sn, &cs);
    float x0 = bf2f(r[col]), x1 = bf2f(r[col + 128]);
    Qb[(long)row*HID + col]       = f2bf(x0*cs - x1*sn);
    Qb[(long)row*HID + col + 128] = f2bf(x1*cs + x0*sn);
  }
  if (tid < 128){
    int d = tid;
    float inv = (float)exp((double)d * -0.07195578415606393);
    float ang = pos * inv;
    float sn, cs; sincosf(ang, &sn, &cs);
    float x0 = bf2f(r[HID + d]), x1 = bf2f(r[HID + d + 128]);
    Kb[(long)row*HDIM + d]       = f2bf(x0*cs - x1*sn);
    Kb[(long)row*HDIM + d + 128] = f2bf(x1*cs + x0*sn);
  }
  {
    int d = tid;                      // v transpose-copy (bf16 bits unchanged)
    VT[((long)b*HDIM + d)*SEQ + s] = r[HID + HDIM + d];
  }
}

// ------------- fused softmax + PV:  P = softmax(S) in place, AO = P @ V -------------
// One 32-row q-strip per block; 2-deep pipeline with counted vmcnt (loads stay
// in flight across raw s_barriers). Per-wave vmem ledger per iter:
//   entry [st(2), P_k(2), V_k(8)] --vmcnt(8)--> [V_k(8)] ; +st(2) +P_{k+1}(2)
//   +V_{k+1}(8) --vmcnt(12)--> [st(2), P_{k+1}(2), V_{k+1}(8)]   (last: vmcnt(2))
__global__ __launch_bounds__(256)
void k_pvsm(float* __restrict__ S, const unsigned short* __restrict__ VT,
            unsigned short* __restrict__ AOb, const float* __restrict__ part){
  constexpr int QB = 32, BK = 64;
  int bh = blockIdx.x; int b = bh >> 3, h = bh & 7;
  int qtile = 63 - (int)blockIdx.z;           // longest strips dispatch first
  int qbase = qtile * QB;
  int kceil = (qbase & ~63) + 64;
  int iters = kceil >> 6;

  float* Sh = S + (long)bh * SEQ * SEQ;
  const unsigned short* Vb = VT + (long)b * HDIM * SEQ;
  const float* pmb = part + (long)bh * NPTILE * SEQ;
  const float* plb = pmb + (long)NBH * NPTILE * SEQ;

  __shared__ unsigned short lA[QB*BK];        // P tile bf16 (32x64), swizzled (4KB)
  __shared__ unsigned short lB[2*HDIM*BK];    // V tile bf16 (256x64) x2 (64KB)
  __shared__ float mlm[QB], mli[QB];

  int tid = threadIdx.x, lane = tid & 63, w = tid >> 6;
  int prow = tid >> 3, c8 = tid & 7;          // P-stage: 8 thr/row, 8 f32 each
  int vswz = ((lane & 7) ^ ((lane >> 3) & 7)) * 8;  // pre-swizzled V source col

  // ---- phase A: combine per-tile partials -> (m, 1/l) per row ----
  {
    int r = qbase + prow;
    float m = BIGNEG, l = 0.f;
    int nt = (r >> 6) + 1;
    for (int tc = c8; tc < nt; tc += 8){
      float mt = pmb[(long)tc*SEQ + r], lt = plb[(long)tc*SEQ + r];
      float nm = fmaxf(m, mt);
      l = l*__expf(m - nm) + lt*__expf(mt - nm);
      m = nm;
    }
    #pragma unroll
    for (int off = 1; off < 8; off <<= 1){
      float om = __shfl_xor(m, off), ol = __shfl_xor(l, off);
      float nm = fmaxf(m, om);
      l = l*__expf(m - nm) + ol*__expf(om - nm);
      m = nm;
    }
    if (c8 == 0){ mlm[prow] = m; mli[prow] = 1.0f / l; }
  }
  __syncthreads();    // full drain: vmem ledger starts at 0

  float pm  = mlm[prow];
  float pil = mli[prow];
  int   rglob = qbase + prow;
  float* prowp = Sh + (long)rglob * SEQ;

  f32x4 acc[2][4];
  #pragma unroll
  for (int m = 0; m < 2; ++m)
    #pragma unroll
    for (int n = 0; n < 4; ++n)
      #pragma unroll
      for (int q = 0; q < 4; ++q) acc[m][n][q] = 0.f;

#define STAGE_V(k0_, buf_)                                                     \
  { _Pragma("unroll")                                                          \
    for (int t = 0; t < 8; ++t){                                               \
      int seg = w*8 + t;                                                       \
      const unsigned short* src = Vb + (long)(seg*8 + (lane >> 3))*SEQ + (k0_) + vswz; \
      gload16(src, (char*)lB + (buf_)*32768 + seg*1024);                       \
    } }

  // ---- prologue: P0 loads (+2), V0 loads (+8) ----
  f32x4 x0 = *(const f32x4*)(prowp + c8*8);
  f32x4 x1 = *(const f32x4*)(prowp + c8*8 + 4);
  STAGE_V(0, 0)
  int cur = 0;

  for (int it = 0; it < iters; ++it){
    int k0 = it * BK;
    asm volatile("s_waitcnt vmcnt(8)" ::: "memory");   // P_k ready
    // normalize: p = exp(s-m)/l (exact 0 in masked cols), writeback + LDS
    u16x8 u; f32x4 y0, y1;
    #pragma unroll
    for (int j = 0; j < 4; ++j){
      float p0 = (k0 + c8*8 + j     <= rglob) ? __expf(x0[j] - pm) * pil : 0.f;
      float p1 = (k0 + c8*8 + 4 + j <= rglob) ? __expf(x1[j] - pm) * pil : 0.f;
      y0[j] = p0; y1[j] = p1;
      u[j] = f2bf(p0); u[4+j] = f2bf(p1);
    }
    *(f32x4*)(prowp + k0 + c8*8)     = y0;             // +2 stores
    *(f32x4*)(prowp + k0 + c8*8 + 4) = y1;
    { int kb = (c8*16) ^ ((prow & 7) << 4);
      *(u16x8*)((char*)lA + prow*128 + kb) = u; }      // ds_write
    if (it + 1 < iters){
      int k1 = k0 + BK;
      x0 = *(const f32x4*)(prowp + k1 + c8*8);         // +2 loads
      x1 = *(const f32x4*)(prowp + k1 + c8*8 + 4);
      STAGE_V(k1, cur^1)                               // +8 loads
      asm volatile("s_waitcnt vmcnt(12)" ::: "memory"); // retires exactly V_k
    } else {
      asm volatile("s_waitcnt vmcnt(2)" ::: "memory");  // retires V_k (stores pend)
    }
    asm volatile("s_waitcnt lgkmcnt(0)" ::: "memory");  // lA writes visible
    __builtin_amdgcn_s_barrier();

    const char* lBc = (const char*)lB + cur*32768;
    __builtin_amdgcn_s_setprio(1);
    #pragma unroll
    for (int kk = 0; kk < 2; ++kk){
      bf16x8 af[2];
      #pragma unroll
      for (int m = 0; m < 2; ++m){
        int row = m*16 + (lane & 15);
        int kb = (kk*64 + (lane >> 4)*16) ^ ((row & 7) << 4);
        af[m] = *(const bf16x8*)((const char*)lA + row*128 + kb);
      }
      #pragma unroll
      for (int n = 0; n < 4; ++n){
        int vr = w*64 + n*16 + (lane & 15);
        int kb = (kk*64 + (lane >> 4)*16) ^ ((vr & 7) << 4);
        bf16x8 bfr = *(const bf16x8*)(lBc + vr*128 + kb);
        acc[0][n] = __builtin_amdgcn_mfma_f32_16x16x32_bf16(af[0], bfr, acc[0][n], 0, 0, 0);
        acc[1][n] = __builtin_amdgcn_mfma_f32_16x16x32_bf16(af[1], bfr, acc[1][n], 0, 0, 0);
      }
    }
    __builtin_amdgcn_s_setprio(0);
    __builtin_amdgcn_s_barrier();                      // lA/lB[cur] reusable
    cur ^= 1;
  }
#undef STAGE_V

  // ---- zero tail (masked region of attn_weights) ----
  {
    f32x4 z4; z4[0]=0.f; z4[1]=0.f; z4[2]=0.f; z4[3]=0.f;
    for (int c0 = kceil; c0 < SEQ; c0 += BK){
      *(f32x4*)(prowp + c0 + c8*8)     = z4;
      *(f32x4*)(prowp + c0 + c8*8 + 4) = z4;
    }
  }

  // ---- epilogue: O -> AOb (bf16) ----
  #pragma unroll
  for (int m = 0; m < 2; ++m){
    #pragma unroll
    for (int ri = 0; ri < 4; ++ri){
      int row = qbase + m*16 + (lane >> 4)*4 + ri;
      long gr = (long)b*SEQ + row;
      #pragma unroll
      for (int n = 0; n < 4; ++n){
        int col = w*64 + n*16 + (lane & 15);
        AOb[gr*HID + h*HDIM + col] = f2bf(acc[m][n][ri]);
      }
    }
  }
}

// ---------------- generic 128x128 MFMA GEMM, C = A @ BT^T ----------------
// GM_SCORES additionally emits per-(row, 64-col-tile) (max, sumexp) partials.
template<int MODE>
__global__ __launch_bounds__(256)
void gemm_bt(const void* __restrict__ Av, const unsigned short* __restrict__ BT0,
             void* __restrict__ Cv,
             int M, int N, int K, int lda, int ldb, int ldc,
             long a_sb, long a_sh, long b_sb, long b_sh, long c_sb, long c_sh,
             int nH, float scale, float* __restrict__ part){
  constexpr int BM = 128, BN = 128, BK = 32;
  int m0 = blockIdx.x * BM, n0 = blockIdx.y * BN;
  if (MODE == GM_SCORES && n0 > m0 + BM - 1) return;   // fully-masked tile

  int z = blockIdx.z;
  int zb = z / nH, zh = z % nH;

  const unsigned short* A16 = (const unsigned short*)Av + zb*a_sb + zh*a_sh;
  const unsigned short* BT = BT0 + zb*b_sb + zh*b_sh;

  __shared__ unsigned short lA[BM*BK];
  __shared__ unsigned short lB[BN*BK];

  int tid = threadIdx.x, lane = tid & 63, w = tid >> 6;
  int wr = w >> 1, wc = w & 1;
  int lrow = lane & 15, lk = (lane >> 4) * 8;

  f32x4 acc[4][4];
  #pragma unroll
  for (int m = 0; m < 4; ++m)
    #pragma unroll
    for (int n = 0; n < 4; ++n)
      #pragma unroll
      for (int q = 0; q < 4; ++q) acc[m][n][q] = 0.f;

  for (int k0 = 0; k0 < K; k0 += BK){
    #pragma unroll
    for (int t = 0; t < 2; ++t){
      int seg = w*2 + t;
      const unsigned short* src = A16 + (long)(m0 + seg*16 + (lane >> 2))*lda + k0 + (lane & 3)*8;
      gload16(src, &lA[seg*512]);
    }
    #pragma unroll
    for (int t = 0; t < 2; ++t){
      int seg = w*2 + t;
      const unsigned short* src = BT + (long)(n0 + seg*16 + (lane >> 2))*ldb + k0 + (lane & 3)*8;
      gload16(src, &lB[seg*512]);
    }
    __syncthreads();

    bf16x8 af[4], bfr[4];
    #pragma unroll
    for (int m = 0; m < 4; ++m)
      af[m] = *(const bf16x8*)&lA[(wr*64 + m*16 + lrow)*BK + lk];
    #pragma unroll
    for (int n = 0; n < 4; ++n)
      bfr[n] = *(const bf16x8*)&lB[(wc*64 + n*16 + lrow)*BK + lk];
    #pragma unroll
    for (int m = 0; m < 4; ++m)
      #pragma unroll
      for (int n = 0; n < 4; ++n)
        acc[m][n] = __builtin_amdgcn_mfma_f32_16x16x32_bf16(af[m], bfr[n], acc[m][n], 0, 0, 0);
    __syncthreads();
  }

  // ---- epilogue ----
  long cbase = zb*c_sb + zh*c_sh;
  if constexpr (MODE == GM_SCORES){
    int tc = (n0 + wc*64) >> 6;
    float* pm_out = part + ((long)z * NPTILE + tc) * SEQ;
    float* pl_out = pm_out + (long)NBH * NPTILE * SEQ;
    #pragma unroll
    for (int m = 0; m < 4; ++m){
      #pragma unroll
      for (int ri = 0; ri < 4; ++ri){
        int orow = m0 + wr*64 + m*16 + (lane >> 4)*4 + ri;
        float v[4]; bool ok[4];
        float mx = BIGNEG;
        #pragma unroll
        for (int n = 0; n < 4; ++n){
          int ocol = n0 + wc*64 + n*16 + (lane & 15);
          v[n] = acc[m][n][ri] * scale;
          ok[n] = (ocol <= orow);
          if (ok[n]){
            ((float*)Cv)[cbase + (long)orow*ldc + ocol] = v[n];
            mx = fmaxf(mx, v[n]);
          }
        }
        #pragma unroll
        for (int off = 8; off; off >>= 1) mx = fmaxf(mx, __shfl_xor(mx, off));
        float sm = 0.f;
        #pragma unroll
        for (int n = 0; n < 4; ++n) if (ok[n]) sm += __expf(v[n] - mx);
        #pragma unroll
        for (int off = 8; off; off >>= 1) sm += __shfl_xor(sm, off);
        if ((lane & 15) == 0){ pm_out[orow] = mx; pl_out[orow] = sm; }
      }
    }
  } else {
    #pragma unroll
    for (int m = 0; m < 4; ++m){
      #pragma unroll
      for (int ri = 0; ri < 4; ++ri){
        int orow = m0 + wr*64 + m*16 + (lane >> 4)*4 + ri;
        #pragma unroll
        for (int n = 0; n < 4; ++n){
          int ocol = n0 + wc*64 + n*16 + (lane & 15);
          float vv = acc[m][n][ri];
          if (MODE == GM_F32){
            ((float*)Cv)[cbase + (long)orow*ldc + ocol] = vv;
          } else {
            ((unsigned short*)Cv)[cbase + (long)orow*ldc + ocol] = f2bf(vv);
          }
        }
      }
    }
  }
}

extern "C" void kernel_launch(void* const* d_in, const int* in_sizes, int n_in,
                              void* d_out, int out_size, void* d_ws, size_t ws_size,
                              hipStream_t stream){
  const float* hs  = (const float*)d_in[0];
  const int*   pos = (const int*)  d_in[1];
  // d_in[2] = attention_mask: causal, applied analytically — unused.
  const float* Wq  = (const float*)d_in[3];
  const float* Wk  = (const float*)d_in[4];
  const float* Wv  = (const float*)d_in[5];
  const float* Wo  = (const float*)d_in[6];

  float* out  = (float*)d_out;
  float* Sbuf = out + (long)ROWS * HID;       // attn_weights region (B,H,S,S) f32

  unsigned short* wsp   = (unsigned short*)d_ws;
  unsigned short* hsb   = wsp;                                   // 4096x2048 (16.8MB)
  unsigned short* wqkvT = hsb   + (long)ROWS*HID;                // 2560x2048
  unsigned short* woT   = wqkvT + (long)QKVN*HID;                // 2048x2048
  unsigned short* qkvb  = woT   + (long)HID*HID;                 // 4096x2560
  unsigned short* Qb    = qkvb  + (long)ROWS*QKVN;               // 4096x2048
  unsigned short* Kb    = Qb    + (long)ROWS*HID;                // 4096x256
  unsigned short* VT    = Kb    + (long)ROWS*HDIM;               // 2x256x2048
  unsigned short* AOb   = VT    + (long)BATCH*HDIM*SEQ;          // 4096x2048

  // softmax partials (2 x 4MB) alias hsb — hsb is dead after the QKV GEMM.
  float* part = (float*)hsb;

  // 1. converts / weight transposes
  k_f32_to_bf16<<<(ROWS*HID)/(256*16), 256, 0, stream>>>(hs, hsb);
  k_transpose<<<dim3(HID/32,  HID/32), 256, 0, stream>>>(Wq, wqkvT, HID, HID);
  k_transpose<<<dim3(HDIM/32, HID/32), 256, 0, stream>>>(Wk, wqkvT + (long)HID*HID, HDIM, HID);
  k_transpose<<<dim3(HDIM/32, HID/32), 256, 0, stream>>>(Wv, wqkvT + (long)(HID+HDIM)*HID, HDIM, HID);
  k_transpose<<<dim3(HID/32,  HID/32), 256, 0, stream>>>(Wo, woT, HID, HID);

  // 2. QKV projection (bf16 out)
  gemm_bt<GM_BF16><<<dim3(ROWS/128, QKVN/128, 1), 256, 0, stream>>>(
      hsb, wqkvT, qkvb, ROWS, QKVN, HID, HID, HID, QKVN,
      0, 0, 0, 0, 0, 0, 1, 1.f, nullptr);

  // 3. RoPE + split
  k_rope<<<ROWS, 256, 0, stream>>>(qkvb, pos, Qb, Kb, VT);

  // 4. scores = scale * Q K^T (causal) into attn_weights region + (m,l) partials
  gemm_bt<GM_SCORES><<<dim3(SEQ/128, SEQ/128, NBH), 256, 0, stream>>>(
      Qb, Kb, Sbuf, SEQ, SEQ, HDIM, HID, HDIM, SEQ,
      (long)SEQ*HID, (long)HDIM,
      (long)SEQ*HDIM, 0,
      (long)NHEADS*SEQ*SEQ, (long)SEQ*SEQ,
      NHEADS, 0.0625f, part);

  // 5+6. fused softmax (in place, exact zeros) + PV, pipelined
  k_pvsm<<<dim3(NBH, 1, 64), 256, 0, stream>>>(Sbuf, VT, AOb, part);

  // 7. out = attn_out @ Wo (f32 out)
  gemm_bt<GM_F32><<<dim3(ROWS/128, HID/128, 1), 256, 0, stream>>>(
      AOb, woT, out, ROWS, HID, HID, HID, HID, HID,
      0, 0, 0, 0, 0, 0, 1, 1.f, nullptr);
}